// Round 6
// baseline (233.028 us; speedup 1.0000x reference)
//
#include <hip/hip_runtime.h>
#include <stdint.h>

#define D_IN  256
#define D_OUT 128
#define NSEQ  4096
#define NB    16
#define NBLK  1024                      // 64-row tiles; 4 blocks/CU -> all 1024 co-resident
#define LDS_BYTES 34816                 // stage0(16K) + stage1(16K) + wsum(2K)

typedef __bf16 bf16x8 __attribute__((ext_vector_type(8)));
typedef float  f32x4  __attribute__((ext_vector_type(4)));

__device__ __forceinline__ unsigned short f2bf(float f) {
  __bf16 h = (__bf16)f;
  union { __bf16 h; unsigned short u; } c; c.h = h;
  return c.u;
}

// prep: Wa = Wp @ W1 (fp32 accum -> bf16, [n][k] layout), W2 transpose,
// be1 = bp @ W1 + b1, S + cnt zeroed (atomic targets; ws is poisoned between
// iterations so this zeroing is mandatory every launch). Folding Wp@W1 is
// exact math (ReLU is the only nonlinearity).
__global__ __launch_bounds__(256) void prep(
    const float* __restrict__ Wp, const float* __restrict__ W1, const float* __restrict__ W2,
    const float* __restrict__ bp, const float* __restrict__ b1,
    unsigned short* __restrict__ WaT, unsigned short* __restrict__ W2T,
    float* __restrict__ be1, float* __restrict__ S, unsigned int* __restrict__ cnt) {
  int b = blockIdx.x;
  if (b < 128) {
    __shared__ float wp[256];
    int k0 = b * 2;
    wp[threadIdx.x] = Wp[k0 * 128 + threadIdx.x];
    __syncthreads();
    int kk = threadIdx.x >> 7, n = threadIdx.x & 127;
    float s = 0.f;
#pragma unroll 16
    for (int j = 0; j < 128; ++j) s += wp[kk * 128 + j] * W1[j * 128 + n];
    WaT[n * 256 + (k0 + kk)] = f2bf(s);
  } else if (b < 192) {
    int t = (b - 128) * 256 + threadIdx.x;
    int k = t >> 7, n = t & 127;
    W2T[n * 128 + k] = f2bf(W2[t]);
  } else {
    if (threadIdx.x < 128) {
      int n = threadIdx.x;
      float s = b1[n];
#pragma unroll 16
      for (int j = 0; j < 128; ++j) s += bp[j] * W1[j * 128 + n];
      be1[n] = s;
    } else {
      int i = threadIdx.x - 128;
#pragma unroll
      for (int j = 0; j < 16; ++j) S[i * 16 + j] = 0.f;   // 16 x 128 floats
      if (i < 16) cnt[i] = 0u;
    }
  }
}

// Single main kernel (R4 tile structure + batch-scoped spin barrier):
//  - 1024 blocks x 64 rows, 4 blocks/CU => ALL co-resident (verified R3 via
//    occupancy query + successful 1024-block cooperative launch).
//  - All 16 X float4 loads issued before barrier #1 (max MLP -- R5 showed
//    removing this staging costs 20 us). Split-cols waves, B-frags register-
//    prefetched one GEMM ahead (R4's proven layout, byte-identical math).
//  - Col sums: wave partials -> wsum(LDS) -> one atomicAdd per col into
//    S[batch] (device-scope), then a PER-BATCH release/acquire: 64 blocks
//    bump cnt[batch]; poll with s_sleep backoff (bounded: fail-loud absmax,
//    never hang). NOT a grid sync -- R3 measured CG grid.sync at ~100+ us.
//  - After the spin Y3 is STILL IN THE ACCUMULATORS: out = S - (acc+b2)
//    written once in f32 from registers. No Y3 global round-trip, no
//    finalize kernel, no bf16 rounding of Y3.
// LDS swizzle: (row,col) -> row*128 + ((col>>3 ^ (row&15))<<3) + (col&7).
__global__ __launch_bounds__(256, 4) void fused_all(
    const float* __restrict__ X,
    const unsigned short* __restrict__ WaT,
    const unsigned short* __restrict__ W2T,
    const float* __restrict__ be1, const float* __restrict__ b2v,
    float* __restrict__ out, float* __restrict__ S, unsigned int* __restrict__ cnt) {
  extern __shared__ unsigned short smem[];
  unsigned short* st0 = smem;             // X chunk0 (later Y2), 64x128 bf16 swizzled
  unsigned short* st1 = smem + 8192;      // X chunk1
  float* wsum = (float*)(smem + 16384);   // 4 x 128 per-wave col sums

  const int tid  = threadIdx.x;
  const int lane = tid & 63;
  const int w    = tid >> 6;
  const int q    = lane >> 4;
  const int l16  = lane & 15;
  const int blk  = blockIdx.x;
  const int batch = blk >> 6;             // 64 blocks per batch
  const int rowbase = blk * 64;
  const int col0 = w * 32 + l16;
  const int col1 = col0 + 16;

  const float e0  = be1[col0], e1  = be1[col1];
  const float bb0 = b2v[col0], bb1 = b2v[col1];

  f32x4 acc[4][2];
  bf16x8 bA[4][2], bB[4][2];              // [ks][ct]

  // ---- issue ALL 16 X loads up front (both K-chunks in flight) ----
  float4 xv0[8], xv1[8];
#pragma unroll
  for (int it = 0; it < 8; ++it) {
    int i = tid + it * 256;
    int r = i >> 5, c4 = (i & 31) << 2;
    xv0[it] = *(const float4*)(X + (size_t)(rowbase + r) * D_IN + c4);
    xv1[it] = *(const float4*)(X + (size_t)(rowbase + r) * D_IN + 128 + c4);
  }

  // ---- stage chunk0 -> st0, chunk1 -> st1 (bf16, swizzled) ----
#pragma unroll
  for (int it = 0; it < 8; ++it) {
    int i = tid + it * 256;
    int r = i >> 5, c4 = (i & 31) << 2;
    int off = r * 128 + ((((c4 >> 3) ^ (r & 15)) << 3) + (c4 & 7));
    ushort4 u0; u0.x = f2bf(xv0[it].x); u0.y = f2bf(xv0[it].y); u0.z = f2bf(xv0[it].z); u0.w = f2bf(xv0[it].w);
    *(ushort4*)(st0 + off) = u0;
    ushort4 u1; u1.x = f2bf(xv1[it].x); u1.y = f2bf(xv1[it].y); u1.z = f2bf(xv1[it].z); u1.w = f2bf(xv1[it].w);
    *(ushort4*)(st1 + off) = u1;
  }

  // ---- prefetch Wa chunk0 B-frags (L2-hot) ----
#pragma unroll
  for (int ks = 0; ks < 4; ++ks) {
    bA[ks][0] = *(const bf16x8*)(WaT + (size_t)col0 * 256 + ks * 32 + q * 8);
    bA[ks][1] = *(const bf16x8*)(WaT + (size_t)col1 * 256 + ks * 32 + q * 8);
  }
#pragma unroll
  for (int rt = 0; rt < 4; ++rt) {
    acc[rt][0] = (f32x4){0.f, 0.f, 0.f, 0.f};
    acc[rt][1] = (f32x4){0.f, 0.f, 0.f, 0.f};
  }
  __syncthreads();   // #1: st0+st1 ready

  // ---- prefetch Wa chunk1 frags (fly under GEMM-A c0) ----
#pragma unroll
  for (int ks = 0; ks < 4; ++ks) {
    bB[ks][0] = *(const bf16x8*)(WaT + (size_t)col0 * 256 + 128 + ks * 32 + q * 8);
    bB[ks][1] = *(const bf16x8*)(WaT + (size_t)col1 * 256 + 128 + ks * 32 + q * 8);
  }

  // ---- GEMM-A chunk0 (st0, bA) ----
#pragma unroll
  for (int ks = 0; ks < 4; ++ks)
#pragma unroll
    for (int rt = 0; rt < 4; ++rt) {
      bf16x8 a = *(const bf16x8*)(st0 + (rt * 16 + l16) * 128 + (((4 * ks + q) ^ l16) << 3));
      acc[rt][0] = __builtin_amdgcn_mfma_f32_16x16x32_bf16(a, bA[ks][0], acc[rt][0], 0, 0, 0);
      acc[rt][1] = __builtin_amdgcn_mfma_f32_16x16x32_bf16(a, bA[ks][1], acc[rt][1], 0, 0, 0);
    }

  // ---- prefetch W2 frags into bA slots (Wa-c0 frags dead in this wave) ----
#pragma unroll
  for (int ks = 0; ks < 4; ++ks) {
    bA[ks][0] = *(const bf16x8*)(W2T + (size_t)col0 * 128 + ks * 32 + q * 8);
    bA[ks][1] = *(const bf16x8*)(W2T + (size_t)col1 * 128 + ks * 32 + q * 8);
  }

  // ---- GEMM-A chunk1 (st1, bB) ----
#pragma unroll
  for (int ks = 0; ks < 4; ++ks)
#pragma unroll
    for (int rt = 0; rt < 4; ++rt) {
      bf16x8 a = *(const bf16x8*)(st1 + (rt * 16 + l16) * 128 + (((4 * ks + q) ^ l16) << 3));
      acc[rt][0] = __builtin_amdgcn_mfma_f32_16x16x32_bf16(a, bB[ks][0], acc[rt][0], 0, 0, 0);
      acc[rt][1] = __builtin_amdgcn_mfma_f32_16x16x32_bf16(a, bB[ks][1], acc[rt][1], 0, 0, 0);
    }
  __syncthreads();   // #2: all waves done reading st0 (chunk0) -> st0 reusable

  // ---- epilogue A: Y2 = relu(acc + be1) -> st0 ----
#pragma unroll
  for (int rt = 0; rt < 4; ++rt)
#pragma unroll
    for (int r = 0; r < 4; ++r) {
      int row = rt * 16 + q * 4 + r;
      int sw = (row & 15) << 3;
      float v0 = acc[rt][0][r] + e0; v0 = v0 > 0.f ? v0 : 0.f;
      float v1 = acc[rt][1][r] + e1; v1 = v1 > 0.f ? v1 : 0.f;
      st0[row * 128 + ((((col0 >> 3) << 3) ^ sw) + (col0 & 7))] = f2bf(v0);
      st0[row * 128 + ((((col1 >> 3) << 3) ^ sw) + (col1 & 7))] = f2bf(v1);
    }
  __syncthreads();   // #3: Y2 visible to all waves

  // ---- GEMM-B (st0 = Y2, bA = W2 frags) ----
#pragma unroll
  for (int rt = 0; rt < 4; ++rt) {
    acc[rt][0] = (f32x4){0.f, 0.f, 0.f, 0.f};
    acc[rt][1] = (f32x4){0.f, 0.f, 0.f, 0.f};
  }
#pragma unroll
  for (int ks = 0; ks < 4; ++ks)
#pragma unroll
    for (int rt = 0; rt < 4; ++rt) {
      bf16x8 a = *(const bf16x8*)(st0 + (rt * 16 + l16) * 128 + (((4 * ks + q) ^ l16) << 3));
      acc[rt][0] = __builtin_amdgcn_mfma_f32_16x16x32_bf16(a, bA[ks][0], acc[rt][0], 0, 0, 0);
      acc[rt][1] = __builtin_amdgcn_mfma_f32_16x16x32_bf16(a, bA[ks][1], acc[rt][1], 0, 0, 0);
    }

  // ---- epilogue B: col sums of Y3 = acc + b2 (Y3 itself stays in regs) ----
  {
    float s0 = 0.f, s1 = 0.f;
#pragma unroll
    for (int rt = 0; rt < 4; ++rt)
#pragma unroll
      for (int r = 0; r < 4; ++r) {
        s0 += acc[rt][0][r] + bb0;
        s1 += acc[rt][1][r] + bb1;
      }
    s0 += __shfl_down(s0, 16); s0 += __shfl_down(s0, 32);
    s1 += __shfl_down(s1, 16); s1 += __shfl_down(s1, 32);
    if (lane < 16) {
      wsum[w * 128 + col0] = s0;
      wsum[w * 128 + col1] = s1;
    }
  }
  __syncthreads();   // #4: wsum complete

  // ---- block col sums -> device-scope atomicAdd into S[batch] ----
  if (tid < 128) {
    float s = wsum[tid] + wsum[128 + tid] + wsum[256 + tid] + wsum[384 + tid];
    atomicAdd(&S[(size_t)batch * 128 + tid], s);
  }
  __syncthreads();   // #5: implicit vmcnt(0) -> all S-adds complete at coherent point

  // ---- batch-scoped release/acquire: 64 blocks per batch ----
  if (tid == 0) {
    __hip_atomic_fetch_add(&cnt[batch], 1u, __ATOMIC_RELEASE, __HIP_MEMORY_SCOPE_AGENT);
    int guard = 0;
    while (__hip_atomic_load(&cnt[batch], __ATOMIC_ACQUIRE, __HIP_MEMORY_SCOPE_AGENT) < 64u) {
      __builtin_amdgcn_s_sleep(16);     // ~1K cycles backoff
      if (++guard > 200000) break;      // ~fail-loud bound; never hang the bench
    }
  }
  __syncthreads();   // #6: S[batch] final, visible

  // ---- out = S - Y3, straight from registers (f32, no bf16 rounding) ----
  const float sv0 = __hip_atomic_load(&S[(size_t)batch * 128 + col0],
                                      __ATOMIC_RELAXED, __HIP_MEMORY_SCOPE_AGENT);
  const float sv1 = __hip_atomic_load(&S[(size_t)batch * 128 + col1],
                                      __ATOMIC_RELAXED, __HIP_MEMORY_SCOPE_AGENT);
#pragma unroll
  for (int rt = 0; rt < 4; ++rt)
#pragma unroll
    for (int r = 0; r < 4; ++r) {
      size_t row = (size_t)(rowbase + rt * 16 + q * 4 + r);
      out[row * D_OUT + col0] = sv0 - (acc[rt][0][r] + bb0);
      out[row * D_OUT + col1] = sv1 - (acc[rt][1][r] + bb1);
    }
}

extern "C" void kernel_launch(void* const* d_in, const int* in_sizes, int n_in,
                              void* d_out, int out_size, void* d_ws, size_t ws_size,
                              hipStream_t stream) {
  const float* X  = (const float*)d_in[0];
  const float* Wp = (const float*)d_in[1];
  const float* bp = (const float*)d_in[2];
  const float* W1 = (const float*)d_in[3];
  const float* b1 = (const float*)d_in[4];
  const float* W2 = (const float*)d_in[5];
  const float* b2 = (const float*)d_in[6];
  float* out = (float*)d_out;

  char* ws = (char*)d_ws;
  float* S            = (float*)ws;                               // 8 KB (16 x 128)
  unsigned int* cnt   = (unsigned int*)(ws + 8192);               // 64 B (16 counters)
  float* be1          = (float*)(ws + 12288);                     // 4 KB (512 B used)
  unsigned short* WaT = (unsigned short*)(ws + 16384);            // 64 KB (256x128 bf16 [n][k])
  unsigned short* W2T = (unsigned short*)(ws + 16384 + 65536);    // 32 KB

  prep<<<193, 256, 0, stream>>>(Wp, W1, W2, bp, b1, WaT, W2T, be1, S, cnt);
  fused_all<<<NBLK, 256, LDS_BYTES, stream>>>(X, WaT, W2T, be1, b2, out, S, cnt);
}

// Round 7
// 133.523 us; speedup vs baseline: 1.7452x; 1.7452x over previous
//
#include <hip/hip_runtime.h>
#include <stdint.h>

#define D_IN  256
#define D_OUT 128
#define NSEQ  4096
#define NB    16
#define NBLK  1024                      // 64-row tiles; 4 blocks/CU -> all 1024 co-resident
#define LDS_BYTES 34816                 // st0(16K) + st1(16K) + wsum(2K)

typedef __bf16 bf16x8 __attribute__((ext_vector_type(8)));
typedef float  f32x4  __attribute__((ext_vector_type(4)));

__device__ __forceinline__ unsigned short f2bf(float f) {
  __bf16 h = (__bf16)f;
  union { __bf16 h; unsigned short u; } c; c.h = h;
  return c.u;
}
__device__ __forceinline__ float bf2f(unsigned short u) {
  union { unsigned int u; float f; } a; a.u = ((unsigned int)u) << 16;
  return a.f;
}

// prep: Wa = Wp @ W1 (fp32 accum -> bf16, [n][k] layout), W2 transpose,
// be1 = bp @ W1 + b1, S zeroed (atomicAdd target; ws is re-poisoned between
// iterations so zeroing every launch is mandatory). Folding Wp@W1 is exact
// math (ReLU is the only nonlinearity).
__global__ __launch_bounds__(256) void prep(
    const float* __restrict__ Wp, const float* __restrict__ W1, const float* __restrict__ W2,
    const float* __restrict__ bp, const float* __restrict__ b1,
    unsigned short* __restrict__ WaT, unsigned short* __restrict__ W2T,
    float* __restrict__ be1, float* __restrict__ S) {
  int b = blockIdx.x;
  if (b < 128) {
    __shared__ float wp[256];
    int k0 = b * 2;
    wp[threadIdx.x] = Wp[k0 * 128 + threadIdx.x];
    __syncthreads();
    int kk = threadIdx.x >> 7, n = threadIdx.x & 127;
    float s = 0.f;
#pragma unroll 16
    for (int j = 0; j < 128; ++j) s += wp[kk * 128 + j] * W1[j * 128 + n];
    WaT[n * 256 + (k0 + kk)] = f2bf(s);
  } else if (b < 192) {
    int t = (b - 128) * 256 + threadIdx.x;
    int k = t >> 7, n = t & 127;
    W2T[n * 128 + k] = f2bf(W2[t]);
  } else {
    if (threadIdx.x < 128) {
      int n = threadIdx.x;
      float s = b1[n];
#pragma unroll 16
      for (int j = 0; j < 128; ++j) s += bp[j] * W1[j * 128 + n];
      be1[n] = s;
    } else {
      int i = threadIdx.x - 128;
#pragma unroll
      for (int j = 0; j < 16; ++j) S[i * 16 + j] = 0.f;   // 16 x 128 floats
    }
  }
}

// Main (R4 structure, merged GEMM-A phases): 1024 blocks x 64 rows, 4/CU.
//  - Both X chunks staged to LDS BEFORE barrier #1 (single drain for all 16
//    loads), then GEMM-A c0+c1 back-to-back with no mid-barrier. W2 B-frags
//    prefetched into the c0->c1 seam (bA slots dead after c0 issues).
//  - epilogue A -> st0 (safe: #2 guarantees all waves past GEMM-A).
//  - GEMM-B from st0; Y3 -> st1 (safe: all waves past GEMM-A c1 at #2);
//    col sums -> wsum -> one atomicAdd/col into S[batch] (8 KB; replaces the
//    512 KB P array + per-block re-reduction in finalize).
//  - Kernel boundary = the device barrier (R3/R6: ANY in-kernel cross-block
//    sync costs ~100 us on 8 non-coherent XCDs; boundary costs ~2-5 us).
// LDS swizzle: (row,col) -> row*128 + ((col>>3 ^ (row&15))<<3) + (col&7).
template <bool USE_WS>
__global__ __launch_bounds__(256, 4) void fused2(
    const float* __restrict__ X,
    const unsigned short* __restrict__ WaT,
    const unsigned short* __restrict__ W2T,
    const float* __restrict__ be1, const float* __restrict__ b2v,
    unsigned short* __restrict__ Y3, float* __restrict__ out, float* __restrict__ S) {
  extern __shared__ unsigned short smem[];
  unsigned short* st0 = smem;             // X chunk0, later Y2 (swizzled)
  unsigned short* st1 = smem + 8192;      // X chunk1, later Y3 (swizzled)
  float* wsum = (float*)(smem + 16384);   // 4 x 128 per-wave col sums

  const int tid  = threadIdx.x;
  const int lane = tid & 63;
  const int w    = tid >> 6;
  const int q    = lane >> 4;
  const int l16  = lane & 15;
  const int blk  = blockIdx.x;
  const int batch = blk >> 6;             // 64 blocks per batch
  const int rowbase = blk * 64;
  const int col0 = w * 32 + l16;
  const int col1 = col0 + 16;

  const float e0  = be1[col0], e1  = be1[col1];
  const float bb0 = b2v[col0], bb1 = b2v[col1];

  f32x4 acc[4][2];
  bf16x8 bA[4][2], bB[4][2];              // [ks][ct]

  // ---- issue all 16 X loads, stage both chunks -> st0/st1 ----
  float4 xv0[8], xv1[8];
#pragma unroll
  for (int it = 0; it < 8; ++it) {
    int i = tid + it * 256;
    int r = i >> 5, c4 = (i & 31) << 2;
    xv0[it] = *(const float4*)(X + (size_t)(rowbase + r) * D_IN + c4);
    xv1[it] = *(const float4*)(X + (size_t)(rowbase + r) * D_IN + 128 + c4);
  }
#pragma unroll
  for (int it = 0; it < 8; ++it) {
    int i = tid + it * 256;
    int r = i >> 5, c4 = (i & 31) << 2;
    int off = r * 128 + ((((c4 >> 3) ^ (r & 15)) << 3) + (c4 & 7));
    ushort4 u0; u0.x = f2bf(xv0[it].x); u0.y = f2bf(xv0[it].y); u0.z = f2bf(xv0[it].z); u0.w = f2bf(xv0[it].w);
    *(ushort4*)(st0 + off) = u0;
    ushort4 u1; u1.x = f2bf(xv1[it].x); u1.y = f2bf(xv1[it].y); u1.z = f2bf(xv1[it].z); u1.w = f2bf(xv1[it].w);
    *(ushort4*)(st1 + off) = u1;
  }

  // ---- prefetch Wa chunk0 B-frags (L2-hot) ----
#pragma unroll
  for (int ks = 0; ks < 4; ++ks) {
    bA[ks][0] = *(const bf16x8*)(WaT + (size_t)col0 * 256 + ks * 32 + q * 8);
    bA[ks][1] = *(const bf16x8*)(WaT + (size_t)col1 * 256 + ks * 32 + q * 8);
  }
#pragma unroll
  for (int rt = 0; rt < 4; ++rt) {
    acc[rt][0] = (f32x4){0.f, 0.f, 0.f, 0.f};
    acc[rt][1] = (f32x4){0.f, 0.f, 0.f, 0.f};
  }
  __syncthreads();   // #1: st0+st1 ready (single drain of all 16 loads)

  // ---- prefetch Wa chunk1 frags (fly under GEMM-A c0) ----
#pragma unroll
  for (int ks = 0; ks < 4; ++ks) {
    bB[ks][0] = *(const bf16x8*)(WaT + (size_t)col0 * 256 + 128 + ks * 32 + q * 8);
    bB[ks][1] = *(const bf16x8*)(WaT + (size_t)col1 * 256 + 128 + ks * 32 + q * 8);
  }

  // ---- GEMM-A chunk0 (st0, bA) ----
#pragma unroll
  for (int ks = 0; ks < 4; ++ks)
#pragma unroll
    for (int rt = 0; rt < 4; ++rt) {
      bf16x8 a = *(const bf16x8*)(st0 + (rt * 16 + l16) * 128 + (((4 * ks + q) ^ l16) << 3));
      acc[rt][0] = __builtin_amdgcn_mfma_f32_16x16x32_bf16(a, bA[ks][0], acc[rt][0], 0, 0, 0);
      acc[rt][1] = __builtin_amdgcn_mfma_f32_16x16x32_bf16(a, bA[ks][1], acc[rt][1], 0, 0, 0);
    }

  // ---- prefetch W2 frags into bA slots (Wa-c0 frags dead in this wave) ----
#pragma unroll
  for (int ks = 0; ks < 4; ++ks) {
    bA[ks][0] = *(const bf16x8*)(W2T + (size_t)col0 * 128 + ks * 32 + q * 8);
    bA[ks][1] = *(const bf16x8*)(W2T + (size_t)col1 * 128 + ks * 32 + q * 8);
  }

  // ---- GEMM-A chunk1 (st1, bB) -- no barrier needed: st1 ready since #1 ----
#pragma unroll
  for (int ks = 0; ks < 4; ++ks)
#pragma unroll
    for (int rt = 0; rt < 4; ++rt) {
      bf16x8 a = *(const bf16x8*)(st1 + (rt * 16 + l16) * 128 + (((4 * ks + q) ^ l16) << 3));
      acc[rt][0] = __builtin_amdgcn_mfma_f32_16x16x32_bf16(a, bB[ks][0], acc[rt][0], 0, 0, 0);
      acc[rt][1] = __builtin_amdgcn_mfma_f32_16x16x32_bf16(a, bB[ks][1], acc[rt][1], 0, 0, 0);
    }
  __syncthreads();   // #2: all waves past GEMM-A -> st0/st1 reusable

  // ---- epilogue A: Y2 = relu(acc + be1) -> st0 ----
#pragma unroll
  for (int rt = 0; rt < 4; ++rt)
#pragma unroll
    for (int r = 0; r < 4; ++r) {
      int row = rt * 16 + q * 4 + r;
      int sw = (row & 15) << 3;
      float v0 = acc[rt][0][r] + e0; v0 = v0 > 0.f ? v0 : 0.f;
      float v1 = acc[rt][1][r] + e1; v1 = v1 > 0.f ? v1 : 0.f;
      st0[row * 128 + ((((col0 >> 3) << 3) ^ sw) + (col0 & 7))] = f2bf(v0);
      st0[row * 128 + ((((col1 >> 3) << 3) ^ sw) + (col1 & 7))] = f2bf(v1);
    }
  __syncthreads();   // #3: Y2 visible to all waves

  // ---- GEMM-B (st0 = Y2, bA = W2 frags) ----
#pragma unroll
  for (int rt = 0; rt < 4; ++rt) {
    acc[rt][0] = (f32x4){0.f, 0.f, 0.f, 0.f};
    acc[rt][1] = (f32x4){0.f, 0.f, 0.f, 0.f};
  }
#pragma unroll
  for (int ks = 0; ks < 4; ++ks)
#pragma unroll
    for (int rt = 0; rt < 4; ++rt) {
      bf16x8 a = *(const bf16x8*)(st0 + (rt * 16 + l16) * 128 + (((4 * ks + q) ^ l16) << 3));
      acc[rt][0] = __builtin_amdgcn_mfma_f32_16x16x32_bf16(a, bA[ks][0], acc[rt][0], 0, 0, 0);
      acc[rt][1] = __builtin_amdgcn_mfma_f32_16x16x32_bf16(a, bA[ks][1], acc[rt][1], 0, 0, 0);
    }

  // ---- epilogue B: Y3 = acc + b2 -> st1; per-wave col sums -> wsum ----
  {
    float s0 = 0.f, s1 = 0.f;
#pragma unroll
    for (int rt = 0; rt < 4; ++rt)
#pragma unroll
      for (int r = 0; r < 4; ++r) {
        int row = rt * 16 + q * 4 + r;
        int sw = (row & 15) << 3;
        float v0 = acc[rt][0][r] + bb0;
        float v1 = acc[rt][1][r] + bb1;
        s0 += v0; s1 += v1;
        st1[row * 128 + ((((col0 >> 3) << 3) ^ sw) + (col0 & 7))] = f2bf(v0);
        st1[row * 128 + ((((col1 >> 3) << 3) ^ sw) + (col1 & 7))] = f2bf(v1);
      }
    s0 += __shfl_down(s0, 16); s0 += __shfl_down(s0, 32);
    s1 += __shfl_down(s1, 16); s1 += __shfl_down(s1, 32);
    if (lane < 16) {
      wsum[w * 128 + col0] = s0;
      wsum[w * 128 + col1] = s1;
    }
  }
  __syncthreads();   // #4: st1 (Y3) + wsum complete

  // ---- block col sums -> one device-scope atomicAdd per col into S[batch] ----
  if (tid < 128) {
    float s = wsum[tid] + wsum[128 + tid] + wsum[256 + tid] + wsum[384 + tid];
    atomicAdd(&S[(size_t)batch * 128 + tid], s);
  }

  // ---- copy-out tile ----
  if (USE_WS) {
#pragma unroll
    for (int it = 0; it < 4; ++it) {
      int i = tid + it * 256;
      int r = i >> 4, g = i & 15;
      *(uint4*)(Y3 + (size_t)(rowbase + r) * 128 + g * 8) =
          *(const uint4*)(st1 + r * 128 + ((g ^ (r & 15)) << 3));
    }
  } else {
#pragma unroll
    for (int it = 0; it < 8; ++it) {
      int i = tid + it * 256;
      int r = i >> 5, c4 = (i & 31) << 2;
      ushort4 u = *(const ushort4*)(st1 + r * 128 + ((((c4 >> 3) ^ (r & 15)) << 3) + (c4 & 7)));
      float4 v; v.x = bf2f(u.x); v.y = bf2f(u.y); v.z = bf2f(u.z); v.w = bf2f(u.w);
      *(float4*)(out + (size_t)(rowbase + r) * D_OUT + c4) = v;
    }
  }
}

// finalize (ws path): 1024 blocks x 64 rows; S ready (8 KB, LLC-hot); Y3
// reads hit the XCD-local L2 that wrote them (same grid->XCD round-robin).
// out[row][d] = S[b][d] - Y3[row][d].
__global__ __launch_bounds__(256) void finalize_ws(
    float* __restrict__ out, const unsigned short* __restrict__ Y3, const float* __restrict__ S) {
  __shared__ float fs[128];
  const int tid  = threadIdx.x;
  const int row0 = blockIdx.x * 64;
  const int b    = row0 >> 12;
  if (tid < 128) fs[tid] = S[(size_t)b * 128 + tid];
  __syncthreads();

#pragma unroll
  for (int it = 0; it < 4; ++it) {
    int i = tid + it * 256;
    int r = i >> 4, g = (i & 15) * 8;
    size_t base = (size_t)(row0 + r) * 128 + g;
    uint4 u = *(const uint4*)(Y3 + base);
    float4 s0 = *(const float4*)(fs + g);
    float4 s1 = *(const float4*)(fs + g + 4);
    union { unsigned int uu; float f; } t;
    float4 o0, o1;
    t.uu = u.x << 16;          o0.x = s0.x - t.f;
    t.uu = u.x & 0xFFFF0000u;  o0.y = s0.y - t.f;
    t.uu = u.y << 16;          o0.z = s0.z - t.f;
    t.uu = u.y & 0xFFFF0000u;  o0.w = s0.w - t.f;
    t.uu = u.z << 16;          o1.x = s1.x - t.f;
    t.uu = u.z & 0xFFFF0000u;  o1.y = s1.y - t.f;
    t.uu = u.w << 16;          o1.z = s1.z - t.f;
    t.uu = u.w & 0xFFFF0000u;  o1.w = s1.w - t.f;
    *(float4*)(out + base) = o0;
    *(float4*)(out + base + 4) = o1;
  }
}

// fallback finalize: out[row][d] = S[b][d] - out[row][d], in place
__global__ __launch_bounds__(256) void finalize_ip(
    float* __restrict__ out, const float* __restrict__ S) {
  __shared__ float fs[128];
  const int tid  = threadIdx.x;
  const int row0 = blockIdx.x * 64;
  const int b    = row0 >> 12;
  if (tid < 128) fs[tid] = S[(size_t)b * 128 + tid];
  __syncthreads();

#pragma unroll
  for (int it = 0; it < 4; ++it) {
    int i = tid + it * 256;
    int r = i >> 4, g = (i & 15) * 8;
    size_t base = (size_t)(row0 + r) * 128 + g;
    float4 s0 = *(const float4*)(fs + g);
    float4 s1 = *(const float4*)(fs + g + 4);
    float4 y0 = *(const float4*)(out + base);
    float4 y1 = *(const float4*)(out + base + 4);
    float4 o0, o1;
    o0.x = s0.x - y0.x; o0.y = s0.y - y0.y; o0.z = s0.z - y0.z; o0.w = s0.w - y0.w;
    o1.x = s1.x - y1.x; o1.y = s1.y - y1.y; o1.z = s1.z - y1.z; o1.w = s1.w - y1.w;
    *(float4*)(out + base) = o0;
    *(float4*)(out + base + 4) = o1;
  }
}

extern "C" void kernel_launch(void* const* d_in, const int* in_sizes, int n_in,
                              void* d_out, int out_size, void* d_ws, size_t ws_size,
                              hipStream_t stream) {
  const float* X  = (const float*)d_in[0];
  const float* Wp = (const float*)d_in[1];
  const float* bp = (const float*)d_in[2];
  const float* W1 = (const float*)d_in[3];
  const float* b1 = (const float*)d_in[4];
  const float* W2 = (const float*)d_in[5];
  const float* b2 = (const float*)d_in[6];
  float* out = (float*)d_out;

  char* ws = (char*)d_ws;
  float* S            = (float*)ws;                               // 8 KB (16 x 128)
  float* be1          = (float*)(ws + 8192);                      // 4 KB (512 B used)
  unsigned short* WaT = (unsigned short*)(ws + 12288);            // 64 KB (256x128 bf16 [n][k])
  unsigned short* W2T = (unsigned short*)(ws + 12288 + 65536);    // 32 KB
  unsigned short* Y3  = (unsigned short*)(ws + 12288 + 65536 + 32768);  // 16 MB

  const size_t need = 12288 + 65536 + 32768 + (size_t)NB * NSEQ * D_OUT * 2;
  const bool use_ws = ws_size >= need;

  prep<<<193, 256, 0, stream>>>(Wp, W1, W2, bp, b1, WaT, W2T, be1, S);

  if (use_ws) {
    fused2<true><<<NBLK, 256, LDS_BYTES, stream>>>(X, WaT, W2T, be1, b2, Y3, out, S);
    finalize_ws<<<NBLK, 256, 0, stream>>>(out, Y3, S);
  } else {
    fused2<false><<<NBLK, 256, LDS_BYTES, stream>>>(X, WaT, W2T, be1, b2, Y3, out, S);
    finalize_ip<<<NBLK, 256, 0, stream>>>(out, S);
  }
}

// Round 8
// 132.835 us; speedup vs baseline: 1.7543x; 1.0052x over previous
//
#include <hip/hip_runtime.h>
#include <stdint.h>

#define D_IN  256
#define D_OUT 128
#define NSEQ  4096
#define NB    16
#define NBLK  1024                      // 64-row tiles; 4 blocks/CU -> all 1024 co-resident
#define LDS_BYTES 33280                 // st0(16K) + st1(16K) + wsum(512B)

typedef __bf16 bf16x8 __attribute__((ext_vector_type(8)));
typedef float  f32x4  __attribute__((ext_vector_type(4)));

__device__ __forceinline__ unsigned short f2bf(float f) {
  __bf16 h = (__bf16)f;
  union { __bf16 h; unsigned short u; } c; c.h = h;
  return c.u;
}
__device__ __forceinline__ float bf2f(unsigned short u) {
  union { unsigned int u; float f; } a; a.u = ((unsigned int)u) << 16;
  return a.f;
}

// prep: Wa = Wp @ W1 (fp32 accum -> bf16, [n][k] layout), W2 transpose,
// be1 = bp @ W1 + b1, S zeroed (atomicAdd target; ws is re-poisoned between
// iterations so zeroing every launch is mandatory). Folding Wp@W1 is exact
// math (ReLU is the only nonlinearity).
__global__ __launch_bounds__(256) void prep(
    const float* __restrict__ Wp, const float* __restrict__ W1, const float* __restrict__ W2,
    const float* __restrict__ bp, const float* __restrict__ b1,
    unsigned short* __restrict__ WaT, unsigned short* __restrict__ W2T,
    float* __restrict__ be1, float* __restrict__ S) {
  int b = blockIdx.x;
  if (b < 128) {
    __shared__ float wp[256];
    int k0 = b * 2;
    wp[threadIdx.x] = Wp[k0 * 128 + threadIdx.x];
    __syncthreads();
    int kk = threadIdx.x >> 7, n = threadIdx.x & 127;
    float s = 0.f;
#pragma unroll 16
    for (int j = 0; j < 128; ++j) s += wp[kk * 128 + j] * W1[j * 128 + n];
    WaT[n * 256 + (k0 + kk)] = f2bf(s);
  } else if (b < 192) {
    int t = (b - 128) * 256 + threadIdx.x;
    int k = t >> 7, n = t & 127;
    W2T[n * 128 + k] = f2bf(W2[t]);
  } else {
    if (threadIdx.x < 128) {
      int n = threadIdx.x;
      float s = b1[n];
#pragma unroll 16
      for (int j = 0; j < 128; ++j) s += bp[j] * W1[j * 128 + n];
      be1[n] = s;
    } else {
      int i = threadIdx.x - 128;
#pragma unroll
      for (int j = 0; j < 16; ++j) S[i * 16 + j] = 0.f;   // 16 x 128 floats
    }
  }
}

// Main (R7 structure; wsum correctness fix): 1024 blocks x 64 rows, 4/CU.
//  - Both X chunks staged to LDS BEFORE barrier #1 (single drain), GEMM-A
//    c0+c1 back-to-back, W2 B-frags prefetched into the c0->c1 seam.
//  - epilogue A -> st0; GEMM-B from st0; Y3 -> st1; col sums -> wsum ->
//    one atomicAdd/col into S[batch].
//  - wsum FIX (R7 latent bug): waves own DISJOINT col ranges (w*32..+31),
//    so each col is written by exactly ONE wave -> flat wsum[128], direct
//    read. The old wsum[4][128] + 4-term sum read 3 never-written LDS slots
//    per col (passed only because LDS read as zero -- UB, now removed).
//  - Kernel boundary = the device barrier (R3/R6: ANY in-kernel cross-block
//    sync costs ~100 us on 8 non-coherent XCDs; boundary costs ~2-5 us).
// LDS swizzle: (row,col) -> row*128 + ((col>>3 ^ (row&15))<<3) + (col&7).
template <bool USE_WS>
__global__ __launch_bounds__(256, 4) void fused2(
    const float* __restrict__ X,
    const unsigned short* __restrict__ WaT,
    const unsigned short* __restrict__ W2T,
    const float* __restrict__ be1, const float* __restrict__ b2v,
    unsigned short* __restrict__ Y3, float* __restrict__ out, float* __restrict__ S) {
  extern __shared__ unsigned short smem[];
  unsigned short* st0 = smem;             // X chunk0, later Y2 (swizzled)
  unsigned short* st1 = smem + 8192;      // X chunk1, later Y3 (swizzled)
  float* wsum = (float*)(smem + 16384);   // 128 col sums (one writer wave per col)

  const int tid  = threadIdx.x;
  const int lane = tid & 63;
  const int w    = tid >> 6;
  const int q    = lane >> 4;
  const int l16  = lane & 15;
  const int blk  = blockIdx.x;
  const int batch = blk >> 6;             // 64 blocks per batch
  const int rowbase = blk * 64;
  const int col0 = w * 32 + l16;
  const int col1 = col0 + 16;

  const float e0  = be1[col0], e1  = be1[col1];
  const float bb0 = b2v[col0], bb1 = b2v[col1];

  f32x4 acc[4][2];
  bf16x8 bA[4][2], bB[4][2];              // [ks][ct]

  // ---- issue all 16 X loads, stage both chunks -> st0/st1 ----
  float4 xv0[8], xv1[8];
#pragma unroll
  for (int it = 0; it < 8; ++it) {
    int i = tid + it * 256;
    int r = i >> 5, c4 = (i & 31) << 2;
    xv0[it] = *(const float4*)(X + (size_t)(rowbase + r) * D_IN + c4);
    xv1[it] = *(const float4*)(X + (size_t)(rowbase + r) * D_IN + 128 + c4);
  }
#pragma unroll
  for (int it = 0; it < 8; ++it) {
    int i = tid + it * 256;
    int r = i >> 5, c4 = (i & 31) << 2;
    int off = r * 128 + ((((c4 >> 3) ^ (r & 15)) << 3) + (c4 & 7));
    ushort4 u0; u0.x = f2bf(xv0[it].x); u0.y = f2bf(xv0[it].y); u0.z = f2bf(xv0[it].z); u0.w = f2bf(xv0[it].w);
    *(ushort4*)(st0 + off) = u0;
    ushort4 u1; u1.x = f2bf(xv1[it].x); u1.y = f2bf(xv1[it].y); u1.z = f2bf(xv1[it].z); u1.w = f2bf(xv1[it].w);
    *(ushort4*)(st1 + off) = u1;
  }

  // ---- prefetch Wa chunk0 B-frags (L2-hot) ----
#pragma unroll
  for (int ks = 0; ks < 4; ++ks) {
    bA[ks][0] = *(const bf16x8*)(WaT + (size_t)col0 * 256 + ks * 32 + q * 8);
    bA[ks][1] = *(const bf16x8*)(WaT + (size_t)col1 * 256 + ks * 32 + q * 8);
  }
#pragma unroll
  for (int rt = 0; rt < 4; ++rt) {
    acc[rt][0] = (f32x4){0.f, 0.f, 0.f, 0.f};
    acc[rt][1] = (f32x4){0.f, 0.f, 0.f, 0.f};
  }
  __syncthreads();   // #1: st0+st1 ready (single drain of all 16 loads)

  // ---- prefetch Wa chunk1 frags (fly under GEMM-A c0) ----
#pragma unroll
  for (int ks = 0; ks < 4; ++ks) {
    bB[ks][0] = *(const bf16x8*)(WaT + (size_t)col0 * 256 + 128 + ks * 32 + q * 8);
    bB[ks][1] = *(const bf16x8*)(WaT + (size_t)col1 * 256 + 128 + ks * 32 + q * 8);
  }

  // ---- GEMM-A chunk0 (st0, bA) ----
#pragma unroll
  for (int ks = 0; ks < 4; ++ks)
#pragma unroll
    for (int rt = 0; rt < 4; ++rt) {
      bf16x8 a = *(const bf16x8*)(st0 + (rt * 16 + l16) * 128 + (((4 * ks + q) ^ l16) << 3));
      acc[rt][0] = __builtin_amdgcn_mfma_f32_16x16x32_bf16(a, bA[ks][0], acc[rt][0], 0, 0, 0);
      acc[rt][1] = __builtin_amdgcn_mfma_f32_16x16x32_bf16(a, bA[ks][1], acc[rt][1], 0, 0, 0);
    }

  // ---- prefetch W2 frags into bA slots (Wa-c0 frags dead in this wave) ----
#pragma unroll
  for (int ks = 0; ks < 4; ++ks) {
    bA[ks][0] = *(const bf16x8*)(W2T + (size_t)col0 * 128 + ks * 32 + q * 8);
    bA[ks][1] = *(const bf16x8*)(W2T + (size_t)col1 * 128 + ks * 32 + q * 8);
  }

  // ---- GEMM-A chunk1 (st1, bB) -- no barrier: st1 ready since #1 ----
#pragma unroll
  for (int ks = 0; ks < 4; ++ks)
#pragma unroll
    for (int rt = 0; rt < 4; ++rt) {
      bf16x8 a = *(const bf16x8*)(st1 + (rt * 16 + l16) * 128 + (((4 * ks + q) ^ l16) << 3));
      acc[rt][0] = __builtin_amdgcn_mfma_f32_16x16x32_bf16(a, bB[ks][0], acc[rt][0], 0, 0, 0);
      acc[rt][1] = __builtin_amdgcn_mfma_f32_16x16x32_bf16(a, bB[ks][1], acc[rt][1], 0, 0, 0);
    }
  __syncthreads();   // #2: all waves past GEMM-A -> st0/st1 reusable

  // ---- epilogue A: Y2 = relu(acc + be1) -> st0 ----
#pragma unroll
  for (int rt = 0; rt < 4; ++rt)
#pragma unroll
    for (int r = 0; r < 4; ++r) {
      int row = rt * 16 + q * 4 + r;
      int sw = (row & 15) << 3;
      float v0 = acc[rt][0][r] + e0; v0 = v0 > 0.f ? v0 : 0.f;
      float v1 = acc[rt][1][r] + e1; v1 = v1 > 0.f ? v1 : 0.f;
      st0[row * 128 + ((((col0 >> 3) << 3) ^ sw) + (col0 & 7))] = f2bf(v0);
      st0[row * 128 + ((((col1 >> 3) << 3) ^ sw) + (col1 & 7))] = f2bf(v1);
    }
  __syncthreads();   // #3: Y2 visible to all waves

  // ---- GEMM-B (st0 = Y2, bA = W2 frags) ----
#pragma unroll
  for (int rt = 0; rt < 4; ++rt) {
    acc[rt][0] = (f32x4){0.f, 0.f, 0.f, 0.f};
    acc[rt][1] = (f32x4){0.f, 0.f, 0.f, 0.f};
  }
#pragma unroll
  for (int ks = 0; ks < 4; ++ks)
#pragma unroll
    for (int rt = 0; rt < 4; ++rt) {
      bf16x8 a = *(const bf16x8*)(st0 + (rt * 16 + l16) * 128 + (((4 * ks + q) ^ l16) << 3));
      acc[rt][0] = __builtin_amdgcn_mfma_f32_16x16x32_bf16(a, bA[ks][0], acc[rt][0], 0, 0, 0);
      acc[rt][1] = __builtin_amdgcn_mfma_f32_16x16x32_bf16(a, bA[ks][1], acc[rt][1], 0, 0, 0);
    }

  // ---- epilogue B: Y3 = acc + b2 -> st1; col sums -> wsum (disjoint cols) ----
  {
    float s0 = 0.f, s1 = 0.f;
#pragma unroll
    for (int rt = 0; rt < 4; ++rt)
#pragma unroll
      for (int r = 0; r < 4; ++r) {
        int row = rt * 16 + q * 4 + r;
        int sw = (row & 15) << 3;
        float v0 = acc[rt][0][r] + bb0;
        float v1 = acc[rt][1][r] + bb1;
        s0 += v0; s1 += v1;
        st1[row * 128 + ((((col0 >> 3) << 3) ^ sw) + (col0 & 7))] = f2bf(v0);
        st1[row * 128 + ((((col1 >> 3) << 3) ^ sw) + (col1 & 7))] = f2bf(v1);
      }
    s0 += __shfl_down(s0, 16); s0 += __shfl_down(s0, 32);
    s1 += __shfl_down(s1, 16); s1 += __shfl_down(s1, 32);
    if (lane < 16) {
      wsum[col0] = s0;   // each col has exactly one writer wave
      wsum[col1] = s1;
    }
  }
  __syncthreads();   // #4: st1 (Y3) + wsum complete

  // ---- block col sums -> one device-scope atomicAdd per col into S[batch] ----
  if (tid < 128) {
    atomicAdd(&S[(size_t)batch * 128 + tid], wsum[tid]);
  }

  // ---- copy-out tile ----
  if (USE_WS) {
#pragma unroll
    for (int it = 0; it < 4; ++it) {
      int i = tid + it * 256;
      int r = i >> 4, g = i & 15;
      *(uint4*)(Y3 + (size_t)(rowbase + r) * 128 + g * 8) =
          *(const uint4*)(st1 + r * 128 + ((g ^ (r & 15)) << 3));
    }
  } else {
#pragma unroll
    for (int it = 0; it < 8; ++it) {
      int i = tid + it * 256;
      int r = i >> 5, c4 = (i & 31) << 2;
      ushort4 u = *(const ushort4*)(st1 + r * 128 + ((((c4 >> 3) ^ (r & 15)) << 3) + (c4 & 7)));
      float4 v; v.x = bf2f(u.x); v.y = bf2f(u.y); v.z = bf2f(u.z); v.w = bf2f(u.w);
      *(float4*)(out + (size_t)(rowbase + r) * D_OUT + c4) = v;
    }
  }
}

// finalize (ws path): 1024 blocks x 64 rows; S ready (8 KB, LLC-hot); Y3
// reads hit the XCD-local L2 that wrote them (same grid->XCD round-robin).
// out[row][d] = S[b][d] - Y3[row][d].
__global__ __launch_bounds__(256) void finalize_ws(
    float* __restrict__ out, const unsigned short* __restrict__ Y3, const float* __restrict__ S) {
  __shared__ float fs[128];
  const int tid  = threadIdx.x;
  const int row0 = blockIdx.x * 64;
  const int b    = row0 >> 12;
  if (tid < 128) fs[tid] = S[(size_t)b * 128 + tid];
  __syncthreads();

#pragma unroll
  for (int it = 0; it < 4; ++it) {
    int i = tid + it * 256;
    int r = i >> 4, g = (i & 15) * 8;
    size_t base = (size_t)(row0 + r) * 128 + g;
    uint4 u = *(const uint4*)(Y3 + base);
    float4 s0 = *(const float4*)(fs + g);
    float4 s1 = *(const float4*)(fs + g + 4);
    union { unsigned int uu; float f; } t;
    float4 o0, o1;
    t.uu = u.x << 16;          o0.x = s0.x - t.f;
    t.uu = u.x & 0xFFFF0000u;  o0.y = s0.y - t.f;
    t.uu = u.y << 16;          o0.z = s0.z - t.f;
    t.uu = u.y & 0xFFFF0000u;  o0.w = s0.w - t.f;
    t.uu = u.z << 16;          o1.x = s1.x - t.f;
    t.uu = u.z & 0xFFFF0000u;  o1.y = s1.y - t.f;
    t.uu = u.w << 16;          o1.z = s1.z - t.f;
    t.uu = u.w & 0xFFFF0000u;  o1.w = s1.w - t.f;
    *(float4*)(out + base) = o0;
    *(float4*)(out + base + 4) = o1;
  }
}

// fallback finalize: out[row][d] = S[b][d] - out[row][d], in place
__global__ __launch_bounds__(256) void finalize_ip(
    float* __restrict__ out, const float* __restrict__ S) {
  __shared__ float fs[128];
  const int tid  = threadIdx.x;
  const int row0 = blockIdx.x * 64;
  const int b    = row0 >> 12;
  if (tid < 128) fs[tid] = S[(size_t)b * 128 + tid];
  __syncthreads();

#pragma unroll
  for (int it = 0; it < 4; ++it) {
    int i = tid + it * 256;
    int r = i >> 4, g = (i & 15) * 8;
    size_t base = (size_t)(row0 + r) * 128 + g;
    float4 s0 = *(const float4*)(fs + g);
    float4 s1 = *(const float4*)(fs + g + 4);
    float4 y0 = *(const float4*)(out + base);
    float4 y1 = *(const float4*)(out + base + 4);
    float4 o0, o1;
    o0.x = s0.x - y0.x; o0.y = s0.y - y0.y; o0.z = s0.z - y0.z; o0.w = s0.w - y0.w;
    o1.x = s1.x - y1.x; o1.y = s1.y - y1.y; o1.z = s1.z - y1.z; o1.w = s1.w - y1.w;
    *(float4*)(out + base) = o0;
    *(float4*)(out + base + 4) = o1;
  }
}

extern "C" void kernel_launch(void* const* d_in, const int* in_sizes, int n_in,
                              void* d_out, int out_size, void* d_ws, size_t ws_size,
                              hipStream_t stream) {
  const float* X  = (const float*)d_in[0];
  const float* Wp = (const float*)d_in[1];
  const float* bp = (const float*)d_in[2];
  const float* W1 = (const float*)d_in[3];
  const float* b1 = (const float*)d_in[4];
  const float* W2 = (const float*)d_in[5];
  const float* b2 = (const float*)d_in[6];
  float* out = (float*)d_out;

  char* ws = (char*)d_ws;
  float* S            = (float*)ws;                               // 8 KB (16 x 128)
  float* be1          = (float*)(ws + 8192);                      // 4 KB (512 B used)
  unsigned short* WaT = (unsigned short*)(ws + 12288);            // 64 KB (256x128 bf16 [n][k])
  unsigned short* W2T = (unsigned short*)(ws + 12288 + 65536);    // 32 KB
  unsigned short* Y3  = (unsigned short*)(ws + 12288 + 65536 + 32768);  // 16 MB

  const size_t need = 12288 + 65536 + 32768 + (size_t)NB * NSEQ * D_OUT * 2;
  const bool use_ws = ws_size >= need;

  prep<<<193, 256, 0, stream>>>(Wp, W1, W2, bp, b1, WaT, W2T, be1, S);

  if (use_ws) {
    fused2<true><<<NBLK, 256, LDS_BYTES, stream>>>(X, WaT, W2T, be1, b2, Y3, out, S);
    finalize_ws<<<NBLK, 256, 0, stream>>>(out, Y3, S);
  } else {
    fused2<false><<<NBLK, 256, LDS_BYTES, stream>>>(X, WaT, W2T, be1, b2, Y3, out, S);
    finalize_ip<<<NBLK, 256, 0, stream>>>(out, S);
  }
}